// Round 27
// baseline (407.759 us; speedup 1.0000x reference)
//
#include <hip/hip_runtime.h>

#define D 64
#define K 1024
#define NROWS (32 * 4096)
#define NELEM (NROWS * D)
#define COMMIT 0.25f
#define HDELTA 6e-5f   // DELTA/2 in acc-space (t = -2*acc)
#define RPB 128        // rows per block = 4 waves x 32 rows (R25 geometry)
#define TPB 256
#define CHUNK 128      // codes per staged LDS chunk
#define EPAD 68        // padded code-row stride in ushorts (136B)
#define CBYTES (CHUNK * EPAD * 2)   // 17408 B
#define CAP 16         // candidate list capacity per row

typedef __attribute__((ext_vector_type(8))) short short8v;   // 8 bf16
typedef __attribute__((ext_vector_type(4))) float f32x4;
typedef unsigned long long u64;

#define FORSLOT8(M) M(0) M(1) M(2) M(3) M(4) M(5) M(6) M(7)

static __device__ __forceinline__ float fence(float v) {
    asm("" : "+v"(v));
    return v;
}

// f32 -> bf16 bits, round-to-nearest-even (finite inputs only).
static __device__ __forceinline__ unsigned short f2bf(float f) {
    unsigned u = __float_as_uint(f);
    return (unsigned short)((u + 0x7FFFu + ((u >> 16) & 1u)) >> 16);
}

// numpy pairwise_sum for n=64: 8 accumulators stride 8, then pairwise tree.
static __device__ __forceinline__ float np_sumsq64(const float* __restrict__ e) {
    float r[8];
#pragma unroll
    for (int j = 0; j < 8; ++j) r[j] = fence(e[j] * e[j]);
#pragma unroll
    for (int t = 1; t < 8; ++t)
#pragma unroll
        for (int j = 0; j < 8; ++j) r[j] = r[j] + fence(e[8 * t + j] * e[8 * t + j]);
    return ((r[0] + r[1]) + (r[2] + r[3])) + ((r[4] + r[5]) + (r[6] + r[7]));
}

// Bit-exact reference score: s = fl( fl(R+N) - 2*dot ), dot = ascending-i
// sequential FMA chain (validated absmax=0 in R2..R26).
static __device__ __forceinline__ float exact_score(
    const float* __restrict__ xrow, const float* __restrict__ erow, float R,
    float N) {
    float a = 0.0f;
#pragma unroll
    for (int i = 0; i < D; ++i) a = __builtin_fmaf(xrow[i], erow[i], a);
    return (R + N) - 2.0f * a;
}

// ---------------- Kernel 1: prep (padded bf16 table) ----------------
// e_pad row k (68 ushorts = 136B): [0..63] bf16(e_k), [64..65] float(-N_k/2),
// [66..67] zero. Linear layout enables global_load_lds; N recovered exactly
// as -2*pad (validated R23/R26).
__global__ void prep_emb_kernel(const float* __restrict__ emb,
                                unsigned short* __restrict__ e_pad,
                                float* __restrict__ loss_slot) {
    int k = blockIdx.x * blockDim.x + threadIdx.x;
    if (k == 0) *loss_slot = 0.0f;
    if (k >= K) return;
    float n = np_sumsq64(emb + k * D);
    const float* e = emb + k * D;
    unsigned short* row = e_pad + k * EPAD;
#pragma unroll
    for (int i = 0; i < D; ++i) row[i] = f2bf(e[i]);
    float nh = -0.5f * n;   // exact scaling
    unsigned nb = __float_as_uint(nh);
    row[64] = (unsigned short)(nb & 0xFFFFu);
    row[65] = (unsigned short)(nb >> 16);
    row[66] = 0;
    row[67] = 0;
}

// async global->LDS: gptr per-lane, lptr wave-uniform (dest = base + lane*SZ)
#define GLDS(SRC, DST, SZ)                                                  \
    __builtin_amdgcn_global_load_lds(                                       \
        (const __attribute__((address_space(1))) unsigned int*)(SRC),       \
        (__attribute__((address_space(3))) unsigned int*)(DST), SZ, 0, 0)

// ---------------- Kernel 2: SINGLE-PASS MFMA argmin, R25 geometry -----------
// EXACT R25 geometry (TPB=256, 4 waves x 32 rows, 8 slots, same STAGE/LDS --
// the validated 73.5us machine); only change: pass B eliminated. Chunk 0 is
// primed max-only (it stays in LDS -- no restage), per-slot thresholds are
// frozen, then ONE collect+running-max pass covers all 8 chunks, tightening
// thresholds after each. Lagged-max <= final-max => collected set is a
// SUPERSET of the final-threshold set => identical exact-rescue => bit-exact
// (structural). In-loop per-element work = R25 pass B's validated CHK + one
// fmaxf. Work: 9 chunk-scans + 8 stages vs R25's 16 + 16.
// (R26 lesson: the 64-rows/wave bundling -- VGPR 136, occ 11% -- was the
// regression, not single-pass; this isolates the lever.)
__global__ __launch_bounds__(TPB, 1) void argmin_kernel(
    const float* __restrict__ x, const float* __restrict__ emb,
    const unsigned short* __restrict__ e_pad, float* __restrict__ out_q,
    float* __restrict__ idx_f, float* __restrict__ loss_slot) {
    const int tid = threadIdx.x;
    const int l = tid & 63;
    const int w = tid >> 6;                        // 0..3
    const int col = l & 15;
    const int koff = (l >> 4) * 8;                 // elements
    const int blockrow = blockIdx.x * RPB;
    const int wrow = blockrow + w * 32;            // wave-private 32 rows

    __shared__ unsigned short eB[CHUNK * EPAD];    // 17,408 B
    __shared__ int cnt[RPB];                       // 512 B
    __shared__ unsigned short clist[RPB][CAP];     // 4,096 B
    __shared__ int bidx[RPB];                      // 512 B
    __shared__ float wsum[4];

    // ---- A-fragments: bf16(x), named SSA. Layout (16x16x32): row = col,
    // k = h*32 + koff + i; B uses the same per-lane permutation (validated).
#define DECL_A(rt, h)                                                       \
    short8v Ahi_##rt##_##h;                                                 \
    { const float* p = x + (size_t)(wrow + rt * 16 + col) * D + h * 32 + koff; \
      float4 q0 = *(const float4*)p, q1 = *(const float4*)(p + 4);          \
      Ahi_##rt##_##h[0] = (short)f2bf(q0.x);                                \
      Ahi_##rt##_##h[1] = (short)f2bf(q0.y);                                \
      Ahi_##rt##_##h[2] = (short)f2bf(q0.z);                                \
      Ahi_##rt##_##h[3] = (short)f2bf(q0.w);                                \
      Ahi_##rt##_##h[4] = (short)f2bf(q1.x);                                \
      Ahi_##rt##_##h[5] = (short)f2bf(q1.y);                                \
      Ahi_##rt##_##h[6] = (short)f2bf(q1.z);                                \
      Ahi_##rt##_##h[7] = (short)f2bf(q1.w); }
    DECL_A(0, 0) DECL_A(0, 1) DECL_A(1, 0) DECL_A(1, 1)

    // slot s = rt*4 + r -> row-within-wave (s/4)*16 + (l>>4)*4 + (s%4)
#define SLOTROW(s) (((s) / 4) * 16 + (l >> 4) * 4 + ((s) % 4))

    // Linear async copy of one 17408B chunk: 4x16B + 1x4B glds per thread
    // (R25's validated STAGE).
#define STAGE(c)                                                            \
    {                                                                       \
        const char* src = (const char*)e_pad + (size_t)(c) * CBYTES;        \
        char* dst = (char*)eB;                                              \
        _Pragma("unroll")                                                   \
        for (int i = 0; i < 4; ++i) {                                       \
            int off = w * 1024 + i * 4096;                                  \
            GLDS(src + off + l * 16, dst + off, 16);                        \
        }                                                                   \
        { int off4 = 16384 + w * 256;                                       \
          GLDS(src + off4 + l * 4, dst + off4, 4); }                        \
    }

    STAGE(0)
    if (tid < RPB) cnt[tid] = 0;
    __syncthreads();   // drains vmcnt(0): chunk 0 + cnt visible

    // ---- per-slot running max (named SSA) ----
#define DECL_MA(s) float mA_##s = -3.402823466e+38f;
    FORSLOT8(DECL_MA)

    // =================== PRIME: chunk 0 max-only ===================
#define PRM(rt, sA, sB, sC, sD)                                             \
    { f32x4 acc = {Nc, Nc, Nc, Nc};                                         \
      acc = __builtin_amdgcn_mfma_f32_16x16x32_bf16(Ahi_##rt##_0, Bhi0, acc, 0, 0, 0); \
      acc = __builtin_amdgcn_mfma_f32_16x16x32_bf16(Ahi_##rt##_1, Bhi1, acc, 0, 0, 0); \
      mA_##sA = fmaxf(mA_##sA, acc[0]);                                     \
      mA_##sB = fmaxf(mA_##sB, acc[1]);                                     \
      mA_##sC = fmaxf(mA_##sC, acc[2]);                                     \
      mA_##sD = fmaxf(mA_##sD, acc[3]); }
#pragma unroll 2
    for (int nt = 0; nt < 8; ++nt) {
        const int cc = nt * 16 + col;
        const short8v Bhi0 = *(const short8v*)(&eB[cc * EPAD + koff]);
        const short8v Bhi1 = *(const short8v*)(&eB[cc * EPAD + 32 + koff]);
        const float Nc = *(const float*)(&eB[cc * EPAD + 64]);
        PRM(0, 0, 1, 2, 3) PRM(1, 4, 5, 6, 7)
    }
    // cross-lane merge (16-lane groups) + frozen thresholds
#define BFA(s)                                                              \
    mA_##s = fmaxf(mA_##s, __shfl_xor(mA_##s, 1));                          \
    mA_##s = fmaxf(mA_##s, __shfl_xor(mA_##s, 2));                          \
    mA_##s = fmaxf(mA_##s, __shfl_xor(mA_##s, 4));                          \
    mA_##s = fmaxf(mA_##s, __shfl_xor(mA_##s, 8));
    FORSLOT8(BFA)
#define DECL_THR(s) float thr_##s = mA_##s - HDELTA;
    FORSLOT8(DECL_THR)
#define UPD_THR(s) thr_##s = mA_##s - HDELTA;

    // ============ SINGLE PASS: collect + running max over 8 chunks ==========
#define CH(s, av)                                                           \
    { if ((av) >= thr_##s) {                                                \
          int row_ = w * 32 + SLOTROW(s);                                   \
          int pos_ = atomicAdd(&cnt[row_], 1);                              \
          if (pos_ < CAP) clist[row_][pos_] = (unsigned short)code_;        \
      }                                                                     \
      mA_##s = fmaxf(mA_##s, (av)); }
#define COLL(rt, sA, sB, sC, sD)                                            \
    { f32x4 acc = {Nc, Nc, Nc, Nc};                                         \
      acc = __builtin_amdgcn_mfma_f32_16x16x32_bf16(Ahi_##rt##_0, Bhi0, acc, 0, 0, 0); \
      acc = __builtin_amdgcn_mfma_f32_16x16x32_bf16(Ahi_##rt##_1, Bhi1, acc, 0, 0, 0); \
      CH(sA, acc[0]) CH(sB, acc[1]) CH(sC, acc[2]) CH(sD, acc[3]) }
    for (int c = 0; c < 8; ++c) {
        if (c > 0) {
            __syncthreads();   // all waves done reading previous chunk
            STAGE(c)
            __syncthreads();   // vmcnt drained: chunk c visible
        }
#pragma unroll 2
        for (int nt = 0; nt < 8; ++nt) {
            const int cc = nt * 16 + col;
            const short8v Bhi0 = *(const short8v*)(&eB[cc * EPAD + koff]);
            const short8v Bhi1 = *(const short8v*)(&eB[cc * EPAD + 32 + koff]);
            const float Nc = *(const float*)(&eB[cc * EPAD + 64]);
            const unsigned code_ = (unsigned)(c * CHUNK + cc);
            COLL(0, 0, 1, 2, 3) COLL(1, 4, 5, 6, 7)
        }
        if (c < 7) {           // tighten thresholds for the next chunk
            FORSLOT8(BFA)
            FORSLOT8(UPD_THR)
        }
    }
    __syncthreads();           // cnt/clist visible

    // ---- select: exact-score candidates, lexicographic (s,k) min ----
    if (tid < RPB) {
        const int row = tid;
        const int grow = blockrow + row;
        const float* xrow = x + (size_t)grow * D;
        const float R = np_sumsq64(xrow);
        const int n = cnt[row];
        float sb = 3.402823466e+38f;
        int kb = 0x7fffffff;
        if (n <= CAP) {
            for (int i = 0; i < n; ++i) {
                int c = clist[row][i];
                float Nk = -2.0f * *(const float*)(&e_pad[c * EPAD + 64]);
                float s = exact_score(xrow, emb + ((size_t)c << 6), R, Nk);
                if (s < sb || (s == sb && c < kb)) { sb = s; kb = c; }
            }
        } else {  // clist overflow (rare): full exact scan
            for (int c = 0; c < K; ++c) {
                float Nk = -2.0f * *(const float*)(&e_pad[c * EPAD + 64]);
                float s = exact_score(xrow, emb + ((size_t)c << 6), R, Nk);
                if (s < sb || (s == sb && c < kb)) { sb = s; kb = c; }
            }
        }
        bidx[row] = kb;
        idx_f[grow] = (float)kb;
    }
    __syncthreads();

    // ---- fused epilogue: gather + straight-through + loss (2 rounds) ----
    float lsum = 0.f;
#pragma unroll
    for (int rr = 0; rr < 2; ++rr) {
        const int row = rr * 64 + (tid >> 2);
        const int d0 = (tid & 3) * 16;
        const int bk = bidx[row];
        const float4* xq =
            (const float4*)(x + (size_t)(blockrow + row) * D + d0);
        const float4* eq = (const float4*)(emb + ((size_t)bk << 6) + d0);
        float4* oq = (float4*)(out_q + (size_t)(blockrow + row) * D + d0);
#pragma unroll
        for (int i = 0; i < 4; ++i) {
            float4 xv = xq[i];
            float4 ev = eq[i];
            float dx = ev.x - xv.x, dy = ev.y - xv.y, dz = ev.z - xv.z,
                  dw = ev.w - xv.w;
            float4 o;
            o.x = xv.x + dx;
            o.y = xv.y + dy;
            o.z = xv.z + dz;
            o.w = xv.w + dw;
            oq[i] = o;
            lsum = __builtin_fmaf(dx, dx, lsum);
            lsum = __builtin_fmaf(dy, dy, lsum);
            lsum = __builtin_fmaf(dz, dz, lsum);
            lsum = __builtin_fmaf(dw, dw, lsum);
        }
    }
#pragma unroll
    for (int o = 32; o > 0; o >>= 1) lsum += __shfl_xor(lsum, o);
    if (l == 0) wsum[w] = lsum;
    __syncthreads();
    if (tid == 0)
        atomicAdd(loss_slot, ((wsum[0] + wsum[1]) + (wsum[2] + wsum[3])) *
                                 ((1.0f + COMMIT) / (float)NELEM));
}

extern "C" void kernel_launch(void* const* d_in, const int* in_sizes, int n_in,
                              void* d_out, int out_size, void* d_ws,
                              size_t ws_size, hipStream_t stream) {
    const float* x = (const float*)d_in[0];    // [32,4096,64] f32
    const float* emb = (const float*)d_in[1];  // [1024,64] f32

    float* out = (float*)d_out;
    float* loss_slot = out;              // out[0]
    float* out_q = out + 1;              // out[1 .. 1+NELEM)
    float* idx_f = out + 1 + NELEM;      // indices as f32

    // workspace: e_pad 139,264 B
    unsigned short* e_pad = (unsigned short*)d_ws;

    prep_emb_kernel<<<(K + 255) / 256, 256, 0, stream>>>(emb, e_pad,
                                                         loss_slot);
    argmin_kernel<<<NROWS / RPB, TPB, 0, stream>>>(x, emb, e_pad, out_q,
                                                   idx_f, loss_slot);
}

// Round 28
// 73.437 us; speedup vs baseline: 5.5525x; 5.5525x over previous
//
#include <hip/hip_runtime.h>

#define D 64
#define K 1024
#define NROWS (32 * 4096)
#define NELEM (NROWS * D)
#define COMMIT 0.25f
#define DELTA 1.2e-4f
#define HDELTA 6e-5f   // DELTA/2 in acc-space (t = -2*acc)
#define RPB 128        // rows per block (32 per wave)
#define CHUNK 128      // codes staged per LDS chunk
#define EPAD 68        // padded code-row stride in ushorts (136B): 2-way banks
#define CBYTES (CHUNK * EPAD * 2)   // 17408 B per staged chunk

typedef __attribute__((ext_vector_type(8))) short short8v;   // 8 bf16
typedef __attribute__((ext_vector_type(4))) float f32x4;
typedef unsigned long long u64;

#define FORSLOT8(M) M(0) M(1) M(2) M(3) M(4) M(5) M(6) M(7)

static __device__ __forceinline__ float fence(float v) {
    asm("" : "+v"(v));
    return v;
}

// f32 -> bf16 bits, round-to-nearest-even (finite inputs only).
static __device__ __forceinline__ unsigned short f2bf(float f) {
    unsigned u = __float_as_uint(f);
    return (unsigned short)((u + 0x7FFFu + ((u >> 16) & 1u)) >> 16);
}

// numpy pairwise_sum for n=64: 8 accumulators stride 8, then pairwise tree.
static __device__ __forceinline__ float np_sumsq64(const float* __restrict__ e) {
    float r[8];
#pragma unroll
    for (int j = 0; j < 8; ++j) r[j] = fence(e[j] * e[j]);
#pragma unroll
    for (int t = 1; t < 8; ++t)
#pragma unroll
        for (int j = 0; j < 8; ++j) r[j] = r[j] + fence(e[8 * t + j] * e[8 * t + j]);
    return ((r[0] + r[1]) + (r[2] + r[3])) + ((r[4] + r[5]) + (r[6] + r[7]));
}

// Bit-exact reference score: s = fl( fl(R+N) - 2*dot ), dot = ascending-i
// sequential FMA chain (validated absmax=0 in R2..R27).
static __device__ __forceinline__ float exact_score(
    const float* __restrict__ xrow, const float* __restrict__ erow, float R,
    float N) {
    float a = 0.0f;
#pragma unroll
    for (int i = 0; i < D; ++i) a = __builtin_fmaf(xrow[i], erow[i], a);
    return (R + N) - 2.0f * a;
}

// ---------------- Kernel 1: prep (padded bf16 table + norms) ----------------
// e_pad row k (68 ushorts = 136B): [0..63] bf16(e_k), [64..65] float(-N_k/2),
// [66..67] zero. Linear chunk layout enables global_load_lds staging.
__global__ void prep_emb_kernel(const float* __restrict__ emb,
                                float* __restrict__ enorm,
                                unsigned short* __restrict__ e_pad,
                                float* __restrict__ loss_slot) {
    int k = blockIdx.x * blockDim.x + threadIdx.x;
    if (k == 0) *loss_slot = 0.0f;
    if (k >= K) return;
    float n = np_sumsq64(emb + k * D);
    enorm[k] = n;
    const float* e = emb + k * D;
    unsigned short* row = e_pad + k * EPAD;
#pragma unroll
    for (int i = 0; i < D; ++i) row[i] = f2bf(e[i]);
    float nh = -0.5f * n;   // exact scaling
    unsigned nb = __float_as_uint(nh);
    row[64] = (unsigned short)(nb & 0xFFFFu);
    row[65] = (unsigned short)(nb >> 16);
    row[66] = 0;
    row[67] = 0;
}

// async global->LDS: gptr per-lane, lptr wave-uniform (dest = base + lane*SZ)
#define GLDS(SRC, DST, SZ)                                                  \
    __builtin_amdgcn_global_load_lds(                                       \
        (const __attribute__((address_space(1))) unsigned int*)(SRC),       \
        (__attribute__((address_space(3))) unsigned int*)(DST), SZ, 0, 0)

// ---------------- Kernel 2: LDS-shared-B 2-pass MFMA argmin, glds staging ---
// R25 kernel restored verbatim (73.5us, absmax=0): 2-pass (fmaxf-only min
// pass, then candidate-collect pass), LDS-shared B with global_load_lds
// linear staging, CHUNK=128 (21KB LDS -> 4 co-resident blocks/CU, the R24
// co-residency regime). EMPIRICAL LAW (R11/12/17/26/27): conditional-atomic/
// index/state-machine work fused into the MFMA loop collapses the schedule
// (R27: 407us, occ 7%); collection must live in its own pass.
__global__ __launch_bounds__(256, 1) void argmin_kernel(
    const float* __restrict__ x, const float* __restrict__ emb,
    const float* __restrict__ enorm, const unsigned short* __restrict__ e_pad,
    float* __restrict__ out_q, float* __restrict__ idx_f,
    float* __restrict__ loss_slot) {
    const int tid = threadIdx.x;
    const int l = tid & 63;
    const int w = tid >> 6;
    const int col = l & 15;
    const int koff = (l >> 4) * 8;                 // elements
    const int blockrow = blockIdx.x * RPB;
    const int wrow = blockrow + w * 32;            // wave-private 32 rows

    __shared__ unsigned short eB[CHUNK * EPAD];    // 17,408 B
    __shared__ int cnt[RPB];
    __shared__ int clist[RPB][4];
    __shared__ int bidx[RPB];
    __shared__ float wsum[4];

    // ---- A-fragments: bf16(x), named SSA. Layout (16x16x32): row = col,
    // k = h*32 + koff + i; B uses the same per-lane permutation (validated).
#define DECL_A(rt, h)                                                       \
    short8v Ahi_##rt##_##h;                                                 \
    { const float* p = x + (size_t)(wrow + rt * 16 + col) * D + h * 32 + koff; \
      float4 q0 = *(const float4*)p, q1 = *(const float4*)(p + 4);          \
      Ahi_##rt##_##h[0] = (short)f2bf(q0.x);                                \
      Ahi_##rt##_##h[1] = (short)f2bf(q0.y);                                \
      Ahi_##rt##_##h[2] = (short)f2bf(q0.z);                                \
      Ahi_##rt##_##h[3] = (short)f2bf(q0.w);                                \
      Ahi_##rt##_##h[4] = (short)f2bf(q1.x);                                \
      Ahi_##rt##_##h[5] = (short)f2bf(q1.y);                                \
      Ahi_##rt##_##h[6] = (short)f2bf(q1.z);                                \
      Ahi_##rt##_##h[7] = (short)f2bf(q1.w); }
    DECL_A(0, 0) DECL_A(0, 1) DECL_A(1, 0) DECL_A(1, 1)

    // slot s = rt*4 + r -> row-within-wave (s/4)*16 + (l>>4)*4 + (s%4)
#define SLOTROW(s) (((s) / 4) * 16 + (l >> 4) * 4 + ((s) % 4))

    // Linear async copy of one 17408B chunk: 4x16B + 1x4B glds per thread.
#define STAGE(c)                                                            \
    {                                                                       \
        const char* src = (const char*)e_pad + (size_t)(c) * CBYTES;        \
        char* dst = (char*)eB;                                              \
        _Pragma("unroll")                                                   \
        for (int i = 0; i < 4; ++i) {                                       \
            int off = w * 1024 + i * 4096;                                  \
            GLDS(src + off + l * 16, dst + off, 16);                        \
        }                                                                   \
        { int off4 = 16384 + w * 256;                                       \
          GLDS(src + off4 + l * 4, dst + off4, 4); }                        \
    }

    // =================== PASS A: fmaxf max over 8 staged chunks =============
#define DECL_MA(s) float mA_##s = -3.402823466e+38f;
    FORSLOT8(DECL_MA)
#define MFMA2A(rt, sA, sB, sC, sD)                                          \
    { f32x4 acc = {Nc, Nc, Nc, Nc};                                         \
      acc = __builtin_amdgcn_mfma_f32_16x16x32_bf16(Ahi_##rt##_0, Bhi0, acc, 0, 0, 0); \
      acc = __builtin_amdgcn_mfma_f32_16x16x32_bf16(Ahi_##rt##_1, Bhi1, acc, 0, 0, 0); \
      mA_##sA = fmaxf(mA_##sA, acc[0]);                                     \
      mA_##sB = fmaxf(mA_##sB, acc[1]);                                     \
      mA_##sC = fmaxf(mA_##sC, acc[2]);                                     \
      mA_##sD = fmaxf(mA_##sD, acc[3]); }
    for (int c = 0; c < 8; ++c) {
        __syncthreads();
        STAGE(c)
        __syncthreads();   // drains vmcnt(0): staged data visible
#pragma unroll 2
        for (int nt = 0; nt < 8; ++nt) {
            const int cc = nt * 16 + col;
            const short8v Bhi0 = *(const short8v*)(&eB[cc * EPAD + koff]);
            const short8v Bhi1 = *(const short8v*)(&eB[cc * EPAD + 32 + koff]);
            const float Nc = *(const float*)(&eB[cc * EPAD + 64]);
            MFMA2A(0, 0, 1, 2, 3) MFMA2A(1, 4, 5, 6, 7)
        }
    }
    // C/D layout: col = l&15 (code), 16-lane groups -> xor 1/2/4/8 butterfly.
#define BFA(s)                                                              \
    mA_##s = fmaxf(mA_##s, __shfl_xor(mA_##s, 1));                          \
    mA_##s = fmaxf(mA_##s, __shfl_xor(mA_##s, 2));                          \
    mA_##s = fmaxf(mA_##s, __shfl_xor(mA_##s, 4));                          \
    mA_##s = fmaxf(mA_##s, __shfl_xor(mA_##s, 8));
    FORSLOT8(BFA)
    // per-slot threshold lives in registers (rows are wave-private)
#define DECL_T(s) const float thr_##s = mA_##s - HDELTA;
    FORSLOT8(DECL_T)
    if (tid < RPB) cnt[tid] = 0;

    // =================== PASS B: candidate collection =======================
#define CHK(s, av)                                                          \
    { if ((av) >= thr_##s) {                                                \
          int row = w * 32 + SLOTROW(s);                                    \
          int pos = atomicAdd(&cnt[row], 1);                                \
          if (pos < 4) clist[row][pos] = code;                              \
      } }
#define MFMA2B(rt, sA, sB, sC, sD)                                          \
    { f32x4 acc = {Nc, Nc, Nc, Nc};                                         \
      acc = __builtin_amdgcn_mfma_f32_16x16x32_bf16(Ahi_##rt##_0, Bhi0, acc, 0, 0, 0); \
      acc = __builtin_amdgcn_mfma_f32_16x16x32_bf16(Ahi_##rt##_1, Bhi1, acc, 0, 0, 0); \
      CHK(sA, acc[0]) CHK(sB, acc[1]) CHK(sC, acc[2]) CHK(sD, acc[3]) }
    for (int c = 0; c < 8; ++c) {
        __syncthreads();
        STAGE(c)
        __syncthreads();
#pragma unroll 2
        for (int nt = 0; nt < 8; ++nt) {
            const int cc = nt * 16 + col;
            const short8v Bhi0 = *(const short8v*)(&eB[cc * EPAD + koff]);
            const short8v Bhi1 = *(const short8v*)(&eB[cc * EPAD + 32 + koff]);
            const float Nc = *(const float*)(&eB[cc * EPAD + 64]);
            const int code = c * CHUNK + cc;
            MFMA2B(0, 0, 1, 2, 3) MFMA2B(1, 4, 5, 6, 7)
        }
    }
    __syncthreads();

    // ---- select / rescue (1 thread per row), bit-exact final answer ----
    if (tid < RPB) {
        const int row = tid;
        const int n = cnt[row];
        int bk;
        if (n == 1) {
            bk = clist[row][0];
        } else {
            const float* xrow = x + (size_t)(blockrow + row) * D;
            const float R = np_sumsq64(xrow);
            float sb = 3.402823466e+38f;
            int kb = 0x7fffffff;
            if (n <= 4) {
                for (int i = 0; i < n; ++i) {
                    int c = clist[row][i];
                    float s = exact_score(xrow, emb + ((size_t)c << 6), R,
                                          enorm[c]);
                    if (s < sb || (s == sb && c < kb)) { sb = s; kb = c; }
                }
            } else {  // clist overflow: full exact scan (essentially never)
                for (int c = 0; c < K; ++c) {
                    float s = exact_score(xrow, emb + ((size_t)c << 6), R,
                                          enorm[c]);
                    if (s < sb || (s == sb && c < kb)) { sb = s; kb = c; }
                }
            }
            bk = kb;
        }
        bidx[row] = bk;
        idx_f[blockrow + row] = (float)bk;
    }
    __syncthreads();

    // ---- fused epilogue: gather + straight-through + loss (2 rounds) ----
    float lsum = 0.f;
#pragma unroll
    for (int rr = 0; rr < 2; ++rr) {
        const int row = rr * 64 + (tid >> 2);
        const int d0 = (tid & 3) * 16;
        const int bk = bidx[row];
        const float4* xq =
            (const float4*)(x + (size_t)(blockrow + row) * D + d0);
        const float4* eq = (const float4*)(emb + ((size_t)bk << 6) + d0);
        float4* oq = (float4*)(out_q + (size_t)(blockrow + row) * D + d0);
#pragma unroll
        for (int i = 0; i < 4; ++i) {
            float4 xv = xq[i];
            float4 ev = eq[i];
            float dx = ev.x - xv.x, dy = ev.y - xv.y, dz = ev.z - xv.z,
                  dw = ev.w - xv.w;
            float4 o;
            o.x = xv.x + dx;
            o.y = xv.y + dy;
            o.z = xv.z + dz;
            o.w = xv.w + dw;
            oq[i] = o;
            lsum = __builtin_fmaf(dx, dx, lsum);
            lsum = __builtin_fmaf(dy, dy, lsum);
            lsum = __builtin_fmaf(dz, dz, lsum);
            lsum = __builtin_fmaf(dw, dw, lsum);
        }
    }
#pragma unroll
    for (int o = 32; o > 0; o >>= 1) lsum += __shfl_xor(lsum, o);
    if (l == 0) wsum[w] = lsum;
    __syncthreads();
    if (tid == 0)
        atomicAdd(loss_slot, ((wsum[0] + wsum[1]) + (wsum[2] + wsum[3])) *
                                 ((1.0f + COMMIT) / (float)NELEM));
}

extern "C" void kernel_launch(void* const* d_in, const int* in_sizes, int n_in,
                              void* d_out, int out_size, void* d_ws,
                              size_t ws_size, hipStream_t stream) {
    const float* x = (const float*)d_in[0];    // [32,4096,64] f32
    const float* emb = (const float*)d_in[1];  // [1024,64] f32

    float* out = (float*)d_out;
    float* loss_slot = out;              // out[0]
    float* out_q = out + 1;              // out[1 .. 1+NELEM)
    float* idx_f = out + 1 + NELEM;      // indices as f32

    // workspace layout: enorm 4KB @0; e_pad 139,264B @4096
    float* enorm = (float*)d_ws;
    unsigned short* e_pad = (unsigned short*)((char*)d_ws + 4096);

    prep_emb_kernel<<<(K + 255) / 256, 256, 0, stream>>>(emb, enorm, e_pad,
                                                         loss_slot);
    argmin_kernel<<<NROWS / RPB, 256, 0, stream>>>(x, emb, enorm, e_pad,
                                                   out_q, idx_f, loss_slot);
}